// Round 1
// baseline (769.097 us; speedup 1.0000x reference)
//
#include <hip/hip_runtime.h>

typedef __attribute__((ext_vector_type(4))) float f32x4;
typedef __attribute__((ext_vector_type(8))) short short8;
typedef __attribute__((ext_vector_type(4))) unsigned short u16x4;
typedef __attribute__((ext_vector_type(8))) unsigned short u16x8;

#define AS1 __attribute__((address_space(1)))
#define AS3 __attribute__((address_space(3)))

__device__ __forceinline__ unsigned short f2bf(float f) {
  unsigned u = __float_as_uint(f);
  return (unsigned short)((u + 0x7FFFu + ((u >> 16) & 1u)) >> 16);
}

// ---------- LayerNorm fp32 -> bf16, written into zero-padded (B, N+6, D) ----------
__global__ __launch_bounds__(256) void ln_kernel(
    const float* __restrict__ x, const float* __restrict__ lw,
    const float* __restrict__ lb, unsigned short* __restrict__ xpad) {
  __shared__ float red[8];
  int row = blockIdx.x;                  // 0..8191
  int b = row >> 12, n = row & 4095;
  const float* xr = x + (size_t)row * 1024;
  int c = threadIdx.x * 4;
  f32x4 v = *(const f32x4*)(xr + c);
  float s = v[0] + v[1] + v[2] + v[3];
  float sq = v[0]*v[0] + v[1]*v[1] + v[2]*v[2] + v[3]*v[3];
#pragma unroll
  for (int off = 32; off; off >>= 1) {
    s  += __shfl_xor(s, off, 64);
    sq += __shfl_xor(sq, off, 64);
  }
  int w = threadIdx.x >> 6;
  if ((threadIdx.x & 63) == 0) { red[w*2] = s; red[w*2+1] = sq; }
  __syncthreads();
  float S  = red[0]+red[2]+red[4]+red[6];
  float SQ = red[1]+red[3]+red[5]+red[7];
  float mean = S * (1.0f/1024.0f);
  float var  = SQ * (1.0f/1024.0f) - mean*mean;
  float rstd = rsqrtf(var + 1e-5f);
  f32x4 wv = *(const f32x4*)(lw + c);
  f32x4 bv = *(const f32x4*)(lb + c);
  u16x4 o;
#pragma unroll
  for (int r = 0; r < 4; ++r) o[r] = f2bf((v[r]-mean)*rstd*wv[r] + bv[r]);
  *(u16x4*)(xpad + (((size_t)(b*4102 + n + 3)) << 10) + c) = o;
}

// ---------- Repack W (O,I,K) fp32 -> Bt (O rows, kk=k*1024+i contiguous) bf16 ----------
__global__ __launch_bounds__(256) void repack_kernel(
    const float* __restrict__ Wk, const float* __restrict__ Wv,
    const float* __restrict__ Wq, unsigned short* __restrict__ Wt) {
  const float* W = (blockIdx.y == 0) ? Wk : (blockIdx.y == 1) ? Wv : Wq;
  unsigned short* out = Wt + (size_t)blockIdx.y * 7168 * 1024;
  int o = blockIdx.x;
  const float* row = W + (size_t)o * 7168;
  unsigned short* orow = out + (size_t)o * 7168;
  for (int kk = threadIdx.x; kk < 7168; kk += 256) {
    int i = kk & 1023, k = kk >> 10;
    orow[kk] = f2bf(row[i*7 + k]);
  }
}

// ---------- Conv-as-GEMM: C(Mr x 1024) = A(Mr x 7168, lda=1024, implicit im2col) x Bt^T ----------
// MODE 0: K output (row-major bf16).  MODE 1: V output transposed per head (Vt[bh*64+d][n]).
// MODE 2: Q (strided rows), bf16 + fp32 outputs.
template <int MODE>
__global__ __launch_bounds__(256) void conv_gemm(
    const unsigned short* __restrict__ Apad,
    const unsigned short* __restrict__ Bt,
    unsigned short* __restrict__ Cb,
    float* __restrict__ Cf) {
  __shared__ unsigned short As[128*32];
  __shared__ unsigned short Bs[128*32];
  const int tid = threadIdx.x;
  const int w = tid >> 6, l = tid & 63;
  const int n0 = blockIdx.x << 7;
  const int r0 = blockIdx.y << 7;
  const int srow = l >> 2, schunk = l & 3;

  size_t abase[2], bbase[2];
#pragma unroll
  for (int p = 0; p < 2; ++p) {
    int r = r0 + ((p*4 + w) << 4) + srow;
    int bb, nn;
    if (MODE == 2) { bb = r >> 10; nn = (r & 1023) << 2; }
    else           { bb = r >> 12; nn = r & 4095; }
    abase[p] = (((size_t)(bb*4102 + nn)) << 10) + schunk*8;
    int nc = n0 + ((p*4 + w) << 4) + srow;
    bbase[p] = (size_t)nc * 7168 + schunk*8;
  }

  f32x4 acc[4][4] = {};
  const int wm = (w >> 1) << 6, wn = (w & 1) << 6;
  const int quad = l >> 4, lc = l & 15;

  for (int k0 = 0; k0 < 7168; k0 += 32) {
    __syncthreads();
#pragma unroll
    for (int p = 0; p < 2; ++p) {
      __builtin_amdgcn_global_load_lds(
          (const AS1 void*)(Apad + abase[p] + k0),
          (AS3 void*)(As + ((p*4 + w) << 9)), 16, 0, 0);
      __builtin_amdgcn_global_load_lds(
          (const AS1 void*)(Bt + bbase[p] + k0),
          (AS3 void*)(Bs + ((p*4 + w) << 9)), 16, 0, 0);
    }
    __syncthreads();
    short8 af[4], bfr[4];
#pragma unroll
    for (int i = 0; i < 4; ++i) {
      af[i]  = *(const short8*)(As + (wm + (i<<4) + lc)*32 + (quad<<3));
      bfr[i] = *(const short8*)(Bs + (wn + (i<<4) + lc)*32 + (quad<<3));
    }
#pragma unroll
    for (int i = 0; i < 4; ++i)
#pragma unroll
      for (int j = 0; j < 4; ++j)
        acc[i][j] = __builtin_amdgcn_mfma_f32_16x16x32_bf16(af[i], bfr[j], acc[i][j], 0, 0, 0);
  }

  if (MODE == 0 || MODE == 2) {
#pragma unroll
    for (int i = 0; i < 4; ++i) {
      int rg = r0 + wm + (i<<4) + quad*4;
#pragma unroll
      for (int j = 0; j < 4; ++j) {
        int cg = n0 + wn + (j<<4) + lc;
#pragma unroll
        for (int rr = 0; rr < 4; ++rr) {
          float vv = acc[i][j][rr];
          size_t off = ((size_t)(rg + rr) << 10) + cg;
          Cb[off] = f2bf(vv);
          if (MODE == 2) Cf[off] = vv;
        }
      }
    }
  } else {  // MODE 1: Vt[(b*16+h)*64+d][n]
#pragma unroll
    for (int i = 0; i < 4; ++i) {
      int r = r0 + wm + (i<<4) + quad*4;
      int bq = r >> 12, ns = r & 4095;
#pragma unroll
      for (int j = 0; j < 4; ++j) {
        int og = n0 + wn + (j<<4) + lc;
        u16x4 pv;
#pragma unroll
        for (int rr = 0; rr < 4; ++rr) pv[rr] = f2bf(acc[i][j][rr]);
        *(u16x4*)(Cb + (((size_t)(bq*1024 + og)) << 12) + ns) = pv;
      }
    }
  }
}

// ---------- Flash attention: per (b,h), 128 queries per block, N-tiles of 64 ----------
// Computes S^T = K·Q^T so softmax row (query m) == lane&15 -> per-lane scalar m/l/alpha.
__global__ __launch_bounds__(256) void attn_kernel(
    const unsigned short* __restrict__ Qb, const unsigned short* __restrict__ Kb,
    const unsigned short* __restrict__ Vt, const float* __restrict__ Qf,
    float* __restrict__ out) {
  __shared__ unsigned short Qs[8192];      // (d-half, 128 m, 32)
  __shared__ unsigned short Ks[4096];      // (d-half, 64 n, 32)
  __shared__ unsigned short Vs[4096];      // (n-half, 64 d, 32)
  __shared__ unsigned short Ps[4*32*80];   // per-wave P (32 m x 64 n, stride 80)
  const int tid = threadIdx.x, w = tid >> 6, l = tid & 63;
  const int qt = blockIdx.x & 7, bh = blockIdx.x >> 3;
  const int b = bh >> 4, h = bh & 15;
  const int m0 = qt << 7;
  const int quad = l >> 4, lc = l & 15;

  const unsigned short* Qg = Qb + (((size_t)(b << 10) + m0) << 10) + (h << 6);
#pragma unroll
  for (int p = 0; p < 4; ++p) {
    int idx = p*256 + tid, r = idx >> 3, c = idx & 7;
    u16x8 v = *(const u16x8*)(Qg + ((size_t)r << 10) + c*8);
    *(u16x8*)(Qs + ((c >> 2) << 12) + r*32 + (c & 3)*8) = v;
  }

  float m_run[2] = {-__builtin_inff(), -__builtin_inff()};
  float l_run[2] = {0.f, 0.f};
  f32x4 oacc[4][2] = {};
  const unsigned short* Kg = Kb + (((size_t)b) << 22) + (h << 6);
  const unsigned short* Vg = Vt + (((size_t)bh) << 18);
  unsigned short* Pw = Ps + w*32*80;

  for (int it = 0; it < 64; ++it) {
    int n0 = it << 6;
    __syncthreads();
#pragma unroll
    for (int p = 0; p < 2; ++p) {
      int idx = p*256 + tid, r = idx >> 3, c = idx & 7;
      u16x8 kv = *(const u16x8*)(Kg + ((size_t)(n0 + r) << 10) + c*8);
      *(u16x8*)(Ks + ((c >> 2) << 11) + r*32 + (c & 3)*8) = kv;
      u16x8 vv = *(const u16x8*)(Vg + ((size_t)r << 12) + n0 + c*8);
      *(u16x8*)(Vs + ((c >> 2) << 11) + r*32 + (c & 3)*8) = vv;
    }
    __syncthreads();

    short8 ak[4][2];
#pragma unroll
    for (int k = 0; k < 2; ++k)
#pragma unroll
      for (int ni = 0; ni < 4; ++ni)
        ak[ni][k] = *(const short8*)(Ks + (k << 11) + ((ni<<4) + lc)*32 + (quad<<3));

#pragma unroll
    for (int mi = 0; mi < 2; ++mi) {
      f32x4 sv[4] = {};
#pragma unroll
      for (int k = 0; k < 2; ++k) {
        short8 bq = *(const short8*)(Qs + (k << 12) + (((w<<5) + (mi<<4) + lc))*32 + (quad<<3));
#pragma unroll
        for (int ni = 0; ni < 4; ++ni)
          sv[ni] = __builtin_amdgcn_mfma_f32_16x16x32_bf16(ak[ni][k], bq, sv[ni], 0, 0, 0);
      }
      float tm = -__builtin_inff();
#pragma unroll
      for (int ni = 0; ni < 4; ++ni)
#pragma unroll
        for (int rr = 0; rr < 4; ++rr) {
          sv[ni][rr] *= 0.125f;
          tm = fmaxf(tm, sv[ni][rr]);
        }
      tm = fmaxf(tm, __shfl_xor(tm, 16, 64));
      tm = fmaxf(tm, __shfl_xor(tm, 32, 64));
      float mnew = fmaxf(m_run[mi], tm);
      float alpha = __expf(m_run[mi] - mnew);
      m_run[mi] = mnew;
      float su = 0.f;
#pragma unroll
      for (int ni = 0; ni < 4; ++ni) {
        u16x4 pv;
#pragma unroll
        for (int rr = 0; rr < 4; ++rr) {
          float pp = __expf(sv[ni][rr] - mnew);
          su += pp;
          pv[rr] = f2bf(pp);
        }
        *(u16x4*)(Pw + ((mi<<4) + lc)*80 + (ni<<4) + (quad<<2)) = pv;
      }
      su += __shfl_xor(su, 16, 64);
      su += __shfl_xor(su, 32, 64);
      l_run[mi] = alpha*l_run[mi] + su;
#pragma unroll
      for (int dt = 0; dt < 4; ++dt)
#pragma unroll
        for (int rr = 0; rr < 4; ++rr)
          oacc[dt][mi][rr] *= alpha;
    }
    __syncthreads();
#pragma unroll
    for (int k = 0; k < 2; ++k) {
      short8 bp[2];
#pragma unroll
      for (int mi = 0; mi < 2; ++mi)
        bp[mi] = *(const short8*)(Pw + ((mi<<4) + lc)*80 + (k<<5) + (quad<<3));
#pragma unroll
      for (int dt = 0; dt < 4; ++dt) {
        short8 av = *(const short8*)(Vs + (k << 11) + ((dt<<4) + lc)*32 + (quad<<3));
#pragma unroll
        for (int mi = 0; mi < 2; ++mi)
          oacc[dt][mi] = __builtin_amdgcn_mfma_f32_16x16x32_bf16(av, bp[mi], oacc[dt][mi], 0, 0, 0);
      }
    }
  }

#pragma unroll
  for (int mi = 0; mi < 2; ++mi) {
    float invl = 1.0f / l_run[mi];
    int m = m0 + (w<<5) + (mi<<4) + lc;
#pragma unroll
    for (int dt = 0; dt < 4; ++dt) {
      int d = (dt<<4) + (quad<<2);
      size_t off = (((size_t)(b << 10) + m) << 10) + (h << 6) + d;
      f32x4 qv = *(const f32x4*)(Qf + off);
      f32x4 ov;
#pragma unroll
      for (int rr = 0; rr < 4; ++rr) ov[rr] = oacc[dt][mi][rr]*invl + qv[rr];
      *(f32x4*)(out + off) = ov;
    }
  }
}

extern "C" void kernel_launch(void* const* d_in, const int* in_sizes, int n_in,
                              void* d_out, int out_size, void* d_ws, size_t ws_size,
                              hipStream_t stream) {
  const float* x  = (const float*)d_in[0];
  const float* lw = (const float*)d_in[1];
  const float* lb = (const float*)d_in[2];
  const float* Wk = (const float*)d_in[3];
  const float* Wv = (const float*)d_in[4];
  const float* Wq = (const float*)d_in[5];
  float* out = (float*)d_out;

  char* ws = (char*)d_ws;
  size_t off = 0;
  unsigned short* xpad = (unsigned short*)(ws + off); off += (size_t)2*4102*1024*2;
  unsigned short* Wt   = (unsigned short*)(ws + off); off += (size_t)3*7168*1024*2;
  unsigned short* Kb   = (unsigned short*)(ws + off); off += (size_t)8192*1024*2;
  unsigned short* Vtb  = (unsigned short*)(ws + off); off += (size_t)8192*1024*2;
  unsigned short* Qb   = (unsigned short*)(ws + off); off += (size_t)2048*1024*2;
  float*          Qf   = (float*)(ws + off);          off += (size_t)2048*1024*4;

  hipMemsetAsync(xpad, 0, (size_t)2*4102*1024*2, stream);
  ln_kernel<<<dim3(8192), dim3(256), 0, stream>>>(x, lw, lb, xpad);
  repack_kernel<<<dim3(1024, 3), dim3(256), 0, stream>>>(Wk, Wv, Wq, Wt);
  conv_gemm<0><<<dim3(8, 64), dim3(256), 0, stream>>>(xpad, Wt,                        Kb,  nullptr);
  conv_gemm<1><<<dim3(8, 64), dim3(256), 0, stream>>>(xpad, Wt + (size_t)7168*1024,    Vtb, nullptr);
  conv_gemm<2><<<dim3(8, 16), dim3(256), 0, stream>>>(xpad, Wt + (size_t)2*7168*1024,  Qb,  Qf);
  attn_kernel<<<dim3(256), dim3(256), 0, stream>>>(Qb, Kb, Vtb, Qf, out);
}

// Round 2
// 676.813 us; speedup vs baseline: 1.1364x; 1.1364x over previous
//
#include <hip/hip_runtime.h>

typedef __attribute__((ext_vector_type(4))) float f32x4;
typedef __attribute__((ext_vector_type(8))) short short8;
typedef __attribute__((ext_vector_type(4))) unsigned short u16x4;
typedef __attribute__((ext_vector_type(8))) unsigned short u16x8;

#define AS1 __attribute__((address_space(1)))
#define AS3 __attribute__((address_space(3)))

__device__ __forceinline__ unsigned short f2bf(float f) {
  unsigned u = __float_as_uint(f);
  return (unsigned short)((u + 0x7FFFu + ((u >> 16) & 1u)) >> 16);
}
__device__ __forceinline__ unsigned short f2bf_fast(float f) {
  return (unsigned short)((__float_as_uint(f) + 0x8000u) >> 16);
}

// ---------- LayerNorm fp32 -> bf16 into zero-padded (B, 3+N+3, D) ----------
__global__ __launch_bounds__(256) void ln_kernel(
    const float* __restrict__ x, const float* __restrict__ lw,
    const float* __restrict__ lb, unsigned short* __restrict__ xpad) {
  __shared__ float red[8];
  int row = blockIdx.x;                  // 0..8191
  int b = row >> 12, n = row & 4095;
  const float* xr = x + (size_t)row * 1024;
  int c = threadIdx.x * 4;
  f32x4 v = *(const f32x4*)(xr + c);
  float s = v[0] + v[1] + v[2] + v[3];
  float sq = v[0]*v[0] + v[1]*v[1] + v[2]*v[2] + v[3]*v[3];
#pragma unroll
  for (int off = 32; off; off >>= 1) {
    s  += __shfl_xor(s, off, 64);
    sq += __shfl_xor(sq, off, 64);
  }
  int w = threadIdx.x >> 6;
  if ((threadIdx.x & 63) == 0) { red[w*2] = s; red[w*2+1] = sq; }
  __syncthreads();
  float S  = red[0]+red[2]+red[4]+red[6];
  float SQ = red[1]+red[3]+red[5]+red[7];
  float mean = S * (1.0f/1024.0f);
  float var  = SQ * (1.0f/1024.0f) - mean*mean;
  float rstd = rsqrtf(var + 1e-5f);
  f32x4 wv = *(const f32x4*)(lw + c);
  f32x4 bv = *(const f32x4*)(lb + c);
  u16x4 o;
#pragma unroll
  for (int r = 0; r < 4; ++r) o[r] = f2bf((v[r]-mean)*rstd*wv[r] + bv[r]);
  *(u16x4*)(xpad + (((size_t)(b*4102 + n + 3)) << 10) + c) = o;
}

// ---------- Repack W (O,I,K) fp32 -> Bt (O rows, kk=k*1024+i) bf16 via LDS ----------
__global__ __launch_bounds__(256) void repack_kernel(
    const float* __restrict__ Wk, const float* __restrict__ Wv,
    const float* __restrict__ Wq, unsigned short* __restrict__ Wt) {
  __shared__ unsigned short t[7168];
  const float* W = (blockIdx.y == 0) ? Wk : (blockIdx.y == 1) ? Wv : Wq;
  int o = blockIdx.x;
  const float* row = W + (size_t)o * 7168;
  unsigned short* orow = Wt + (size_t)blockIdx.y * 7168 * 1024 + (size_t)o * 7168;
#pragma unroll
  for (int p = 0; p < 7; ++p) {
    int idx = p*1024 + threadIdx.x*4;
    f32x4 v = *(const f32x4*)(row + idx);
#pragma unroll
    for (int e = 0; e < 4; ++e) {
      unsigned j = idx + e;
      unsigned i = (j * 149797u) >> 20;   // j/7
      unsigned k = j - i*7;
      t[k*1024 + i] = f2bf(v[e]);
    }
  }
  __syncthreads();
#pragma unroll
  for (int p = 0; p < 7; ++p) {
    int idx = p*1024 + threadIdx.x*4;
    *(u16x4*)(orow + idx) = *(const u16x4*)(t + idx);
  }
}

// ---------- Fused conv GEMMs: y<64 -> K+V block (shared A), y>=64 -> Q block ----------
__global__ __launch_bounds__(256, 2) void conv_fused(
    const unsigned short* __restrict__ Apad,
    const unsigned short* __restrict__ Wt,   // [Wk | Wv | Wq] each 7168*1024
    unsigned short* __restrict__ Kb, unsigned short* __restrict__ Vtb,
    unsigned short* __restrict__ Qb, float* __restrict__ Qf) {
  __shared__ unsigned short As[4096];
  __shared__ unsigned short BsK[4096];
  __shared__ unsigned short BsV[4096];
  const int tid = threadIdx.x;
  const int w = tid >> 6, l = tid & 63;
  const int n0 = blockIdx.x << 7;
  const bool isKV = blockIdx.y < 64;
  const int r0 = (isKV ? blockIdx.y : blockIdx.y - 64) << 7;
  const int srow = l >> 2, schunk = l & 3;
  const unsigned short* BtK = Wt;
  const unsigned short* BtV = Wt + (size_t)7168*1024;
  const unsigned short* BtQ = Wt + (size_t)2*7168*1024;

  size_t abase[2], bbase[2];
#pragma unroll
  for (int p = 0; p < 2; ++p) {
    int r = r0 + ((p*4 + w) << 4) + srow;
    int bb, nn;
    if (isKV) { bb = r >> 12; nn = r & 4095; }
    else      { bb = r >> 10; nn = (r & 1023) << 2; }
    abase[p] = (((size_t)(bb*4102 + nn)) << 10) + schunk*8;
    int nc = n0 + ((p*4 + w) << 4) + srow;
    bbase[p] = (size_t)nc * 7168 + schunk*8;
  }

  const int wm = (w >> 1) << 6, wn = (w & 1) << 6;
  const int quad = l >> 4, lc = l & 15;

  if (isKV) {
    f32x4 accK[4][4] = {}, accV[4][4] = {};
    for (int k0 = 0; k0 < 7168; k0 += 32) {
      __syncthreads();
#pragma unroll
      for (int p = 0; p < 2; ++p) {
        __builtin_amdgcn_global_load_lds((const AS1 void*)(Apad + abase[p] + k0),
                                         (AS3 void*)(As  + ((p*4 + w) << 9)), 16, 0, 0);
        __builtin_amdgcn_global_load_lds((const AS1 void*)(BtK + bbase[p] + k0),
                                         (AS3 void*)(BsK + ((p*4 + w) << 9)), 16, 0, 0);
        __builtin_amdgcn_global_load_lds((const AS1 void*)(BtV + bbase[p] + k0),
                                         (AS3 void*)(BsV + ((p*4 + w) << 9)), 16, 0, 0);
      }
      __syncthreads();
      short8 af[4], bk[4], bv[4];
#pragma unroll
      for (int i = 0; i < 4; ++i) {
        af[i] = *(const short8*)(As  + (wm + (i<<4) + lc)*32 + (quad<<3));
        bk[i] = *(const short8*)(BsK + (wn + (i<<4) + lc)*32 + (quad<<3));
        bv[i] = *(const short8*)(BsV + (wn + (i<<4) + lc)*32 + (quad<<3));
      }
#pragma unroll
      for (int i = 0; i < 4; ++i)
#pragma unroll
        for (int j = 0; j < 4; ++j) {
          accK[i][j] = __builtin_amdgcn_mfma_f32_16x16x32_bf16(af[i], bk[j], accK[i][j], 0, 0, 0);
          accV[i][j] = __builtin_amdgcn_mfma_f32_16x16x32_bf16(af[i], bv[j], accV[i][j], 0, 0, 0);
        }
    }
    // K epilogue: row-major bf16
#pragma unroll
    for (int i = 0; i < 4; ++i) {
      int rg = r0 + wm + (i<<4) + quad*4;
#pragma unroll
      for (int j = 0; j < 4; ++j) {
        int cg = n0 + wn + (j<<4) + lc;
#pragma unroll
        for (int rr = 0; rr < 4; ++rr)
          Kb[((size_t)(rg + rr) << 10) + cg] = f2bf(accK[i][j][rr]);
      }
    }
    // V epilogue: transposed per head Vt[(b*16+h)*64+d][n]
#pragma unroll
    for (int i = 0; i < 4; ++i) {
      int r = r0 + wm + (i<<4) + quad*4;
      int bq = r >> 12, ns = r & 4095;
#pragma unroll
      for (int j = 0; j < 4; ++j) {
        int og = n0 + wn + (j<<4) + lc;
        u16x4 pv;
#pragma unroll
        for (int rr = 0; rr < 4; ++rr) pv[rr] = f2bf(accV[i][j][rr]);
        *(u16x4*)(Vtb + (((size_t)(bq*1024 + og)) << 12) + ns) = pv;
      }
    }
  } else {
    f32x4 acc[4][4] = {};
    for (int k0 = 0; k0 < 7168; k0 += 32) {
      __syncthreads();
#pragma unroll
      for (int p = 0; p < 2; ++p) {
        __builtin_amdgcn_global_load_lds((const AS1 void*)(Apad + abase[p] + k0),
                                         (AS3 void*)(As  + ((p*4 + w) << 9)), 16, 0, 0);
        __builtin_amdgcn_global_load_lds((const AS1 void*)(BtQ + bbase[p] + k0),
                                         (AS3 void*)(BsK + ((p*4 + w) << 9)), 16, 0, 0);
      }
      __syncthreads();
      short8 af[4], bq[4];
#pragma unroll
      for (int i = 0; i < 4; ++i) {
        af[i] = *(const short8*)(As  + (wm + (i<<4) + lc)*32 + (quad<<3));
        bq[i] = *(const short8*)(BsK + (wn + (i<<4) + lc)*32 + (quad<<3));
      }
#pragma unroll
      for (int i = 0; i < 4; ++i)
#pragma unroll
        for (int j = 0; j < 4; ++j)
          acc[i][j] = __builtin_amdgcn_mfma_f32_16x16x32_bf16(af[i], bq[j], acc[i][j], 0, 0, 0);
    }
#pragma unroll
    for (int i = 0; i < 4; ++i) {
      int rg = r0 + wm + (i<<4) + quad*4;
#pragma unroll
      for (int j = 0; j < 4; ++j) {
        int cg = n0 + wn + (j<<4) + lc;
#pragma unroll
        for (int rr = 0; rr < 4; ++rr) {
          float vv = acc[i][j][rr];
          size_t off = ((size_t)(rg + rr) << 10) + cg;
          Qb[off] = f2bf(vv);
          Qf[off] = vv;
        }
      }
    }
  }
}

// ---------- Flash attention, 64 queries/block, no online max (S bounded) ----------
__global__ __launch_bounds__(256) void attn_kernel(
    const unsigned short* __restrict__ Qb, const unsigned short* __restrict__ Kb,
    const unsigned short* __restrict__ Vt, const float* __restrict__ Qf,
    float* __restrict__ out) {
  __shared__ unsigned short Qs[4096];      // (d-half, 64 m, 32)
  __shared__ unsigned short Ks[4096];      // (d-half, 64 n, 32)
  __shared__ unsigned short Vs[4096];      // (n-half, 64 d, 32)
  __shared__ unsigned short Ps[4*16*80];   // per-wave P (16 m x 64 n, stride 80)
  const int tid = threadIdx.x, w = tid >> 6, l = tid & 63;
  const int qt = blockIdx.x & 15, bh = blockIdx.x >> 4;
  const int b = bh >> 4, h = bh & 15;
  const int m0 = qt << 6;
  const int quad = l >> 4, lc = l & 15;
  const float C = 0.18033688011112042f;    // log2(e)/8

  const unsigned short* Qg = Qb + (((size_t)(b << 10) + m0) << 10) + (h << 6);
#pragma unroll
  for (int p = 0; p < 2; ++p) {
    int idx = p*256 + tid, r = idx >> 3, c = idx & 7;
    u16x8 v = *(const u16x8*)(Qg + ((size_t)r << 10) + c*8);
    *(u16x8*)(Qs + ((c >> 2) << 11) + r*32 + (c & 3)*8) = v;
  }

  float l_run = 0.f;
  f32x4 oacc[4] = {};
  const unsigned short* Kg = Kb + (((size_t)b) << 22) + (h << 6);
  const unsigned short* Vg = Vt + (((size_t)bh) << 18);
  unsigned short* Pw = Ps + w*1280;

  for (int it = 0; it < 64; ++it) {
    int n0 = it << 6;
    __syncthreads();
#pragma unroll
    for (int p = 0; p < 2; ++p) {
      int idx = p*256 + tid, r = idx >> 3, c = idx & 7;
      u16x8 kv = *(const u16x8*)(Kg + ((size_t)(n0 + r) << 10) + c*8);
      *(u16x8*)(Ks + ((c >> 2) << 11) + r*32 + (c & 3)*8) = kv;
      u16x8 vv = *(const u16x8*)(Vg + ((size_t)r << 12) + n0 + c*8);
      *(u16x8*)(Vs + ((c >> 2) << 11) + r*32 + (c & 3)*8) = vv;
    }
    __syncthreads();

    short8 ak[4][2];
#pragma unroll
    for (int k = 0; k < 2; ++k)
#pragma unroll
      for (int ni = 0; ni < 4; ++ni)
        ak[ni][k] = *(const short8*)(Ks + (k << 11) + ((ni<<4) + lc)*32 + (quad<<3));

    f32x4 sv[4] = {};
#pragma unroll
    for (int k = 0; k < 2; ++k) {
      short8 bq = *(const short8*)(Qs + (k << 11) + ((w<<4) + lc)*32 + (quad<<3));
#pragma unroll
      for (int ni = 0; ni < 4; ++ni)
        sv[ni] = __builtin_amdgcn_mfma_f32_16x16x32_bf16(ak[ni][k], bq, sv[ni], 0, 0, 0);
    }
    float su = 0.f;
#pragma unroll
    for (int ni = 0; ni < 4; ++ni) {
      u16x4 pv;
#pragma unroll
      for (int rr = 0; rr < 4; ++rr) {
        float pp = __builtin_amdgcn_exp2f(sv[ni][rr] * C);
        su += pp;
        pv[rr] = f2bf_fast(pp);
      }
      *(u16x4*)(Pw + lc*80 + (ni<<4) + (quad<<2)) = pv;
    }
    su += __shfl_xor(su, 16, 64);
    su += __shfl_xor(su, 32, 64);
    l_run += su;
    // Ps is per-wave: compiler-inserted lgkmcnt orders write->read, no barrier
#pragma unroll
    for (int k = 0; k < 2; ++k) {
      short8 bp = *(const short8*)(Pw + lc*80 + (k<<5) + (quad<<3));
#pragma unroll
      for (int dt = 0; dt < 4; ++dt) {
        short8 av = *(const short8*)(Vs + (k << 11) + ((dt<<4) + lc)*32 + (quad<<3));
        oacc[dt] = __builtin_amdgcn_mfma_f32_16x16x32_bf16(av, bp, oacc[dt], 0, 0, 0);
      }
    }
  }

  float invl = 1.0f / l_run;
  int m = m0 + (w<<4) + lc;
#pragma unroll
  for (int dt = 0; dt < 4; ++dt) {
    int d = (dt<<4) + (quad<<2);
    size_t off = (((size_t)(b << 10) + m) << 10) + (h << 6) + d;
    f32x4 qv = *(const f32x4*)(Qf + off);
    f32x4 ov;
#pragma unroll
    for (int rr = 0; rr < 4; ++rr) ov[rr] = oacc[dt][rr]*invl + qv[rr];
    *(f32x4*)(out + off) = ov;
  }
}

extern "C" void kernel_launch(void* const* d_in, const int* in_sizes, int n_in,
                              void* d_out, int out_size, void* d_ws, size_t ws_size,
                              hipStream_t stream) {
  const float* x  = (const float*)d_in[0];
  const float* lw = (const float*)d_in[1];
  const float* lb = (const float*)d_in[2];
  const float* Wk = (const float*)d_in[3];
  const float* Wv = (const float*)d_in[4];
  const float* Wq = (const float*)d_in[5];
  float* out = (float*)d_out;

  char* ws = (char*)d_ws;
  size_t off = 0;
  unsigned short* xpad = (unsigned short*)(ws + off); off += (size_t)2*4102*1024*2;
  unsigned short* Wt   = (unsigned short*)(ws + off); off += (size_t)3*7168*1024*2;
  unsigned short* Kb   = (unsigned short*)(ws + off); off += (size_t)8192*1024*2;
  unsigned short* Vtb  = (unsigned short*)(ws + off); off += (size_t)8192*1024*2;
  unsigned short* Qb   = (unsigned short*)(ws + off); off += (size_t)2048*1024*2;
  float*          Qf   = (float*)(ws + off);          off += (size_t)2048*1024*4;

  // zero only the 3-row pads (front/back per batch)
  for (int b = 0; b < 2; ++b) {
    hipMemsetAsync(xpad + (size_t)b*4102*1024, 0, 3*1024*2, stream);
    hipMemsetAsync(xpad + ((size_t)b*4102 + 4099)*1024, 0, 3*1024*2, stream);
  }
  ln_kernel<<<dim3(8192), dim3(256), 0, stream>>>(x, lw, lb, xpad);
  repack_kernel<<<dim3(1024, 3), dim3(256), 0, stream>>>(Wk, Wv, Wq, Wt);
  conv_fused<<<dim3(8, 80), dim3(256), 0, stream>>>(xpad, Wt, Kb, Vtb, Qb, Qf);
  attn_kernel<<<dim3(512), dim3(256), 0, stream>>>(Qb, Kb, Vtb, Qf, out);
}